// Round 1
// baseline (557.101 us; speedup 1.0000x reference)
//
#include <hip/hip_runtime.h>
#include <hip/hip_bf16.h>

// Problem constants (B=2, S=2048, D=1536, H=12, hd=128)
#define S_LEN   2048
#define DMODEL  1536
#define NBATCH  2
#define NHEADS  12
#define MROWS   (NBATCH * S_LEN)        // 4096
#define NCHUNK  16
#define CHUNK   128                     // S_LEN / NCHUNK

typedef unsigned short u16;
typedef __attribute__((ext_vector_type(8))) short bf16x8;   // 8 bf16 = 4 VGPRs
typedef __attribute__((ext_vector_type(4))) float f32x4;

// round-to-nearest-even fp32 -> bf16 (matches numpy / hardware cvt)
__device__ __forceinline__ u16 f2bf(float x) {
  unsigned u = __float_as_uint(x);
  u += 0x7fffu + ((u >> 16) & 1u);
  return (u16)(u >> 16);
}

// ---------------------------------------------------------------- cvt fp32->bf16
__global__ void cvt_f32_to_bf16(const float4* __restrict__ src,
                                ushort4* __restrict__ dst, int n4) {
  int t = blockIdx.x * blockDim.x + threadIdx.x;
  if (t >= n4) return;
  float4 f = src[t];
  ushort4 o;
  o.x = f2bf(f.x); o.y = f2bf(f.y); o.z = f2bf(f.z); o.w = f2bf(f.w);
  dst[t] = o;
}

// ---------------------------------------------------------------- bf16 GEMM  C = A @ B^T + bias
// A:[M,K] bf16 row-major, B:[N,K] bf16 row-major, C:[M,N] fp32.
// m97 structure: 128x128 tile, BK=32, 4 waves (2x2 of 64x64), 16x16x32 MFMA,
// global_load_lds width=16 staging (LDS dest = wave-uniform base + lane*16B).
__device__ __forceinline__ void gld_lds16(u16* lds, const u16* g) {
  __builtin_amdgcn_global_load_lds(
      (const __attribute__((address_space(1))) unsigned int*)g,
      (__attribute__((address_space(3))) unsigned int*)lds, 16, 0, 0);
}

__global__ __launch_bounds__(256)
void gemm_bt_bias(const u16* __restrict__ A, const u16* __restrict__ B,
                  const float* __restrict__ bias, float* __restrict__ C,
                  int Mdim, int Ndim, int Kdim) {
  __shared__ __align__(16) u16 As[128 * 32];   // row-major, row stride 32 bf16 (64 B)
  __shared__ __align__(16) u16 Bs[128 * 32];

  const int tid  = threadIdx.x;
  const int wave = tid >> 6;
  const int lane = tid & 63;
  const int l15  = lane & 15;
  const int quad = lane >> 4;
  const int bm = blockIdx.y * 128;
  const int bn = blockIdx.x * 128;
  const int wm = (wave >> 1) * 64;
  const int wn = (wave & 1) * 64;

  f32x4 acc[4][4] = {};

  // staging: wave w covers rows [w*32, w*32+32); lane l -> row w*32 + t*16 + l/4, k-off (l&3)*8
  const int srow = wave * 32 + (lane >> 2);
  const int skk  = (lane & 3) * 8;
  const u16* gA = A + (size_t)(bm + srow) * Kdim + skk;
  const u16* gB = B + (size_t)(bn + srow) * Kdim + skk;
  u16* lA = &As[(wave * 32) * 32];
  u16* lB = &Bs[(wave * 32) * 32];
  const size_t rstep16 = (size_t)16 * Kdim;

  for (int k0 = 0; k0 < Kdim; k0 += 32) {
    gld_lds16(lA,           gA + k0);
    gld_lds16(lA + 16 * 32, gA + k0 + rstep16);
    gld_lds16(lB,           gB + k0);
    gld_lds16(lB + 16 * 32, gB + k0 + rstep16);
    __syncthreads();   // drains vmcnt -> LDS tiles complete

    bf16x8 af[4], bfr[4];
#pragma unroll
    for (int i = 0; i < 4; ++i)
      af[i] = *(const bf16x8*)&As[(wm + i * 16 + l15) * 32 + quad * 8];
#pragma unroll
    for (int j = 0; j < 4; ++j)
      bfr[j] = *(const bf16x8*)&Bs[(wn + j * 16 + l15) * 32 + quad * 8];
#pragma unroll
    for (int i = 0; i < 4; ++i)
#pragma unroll
      for (int j = 0; j < 4; ++j)
        acc[i][j] = __builtin_amdgcn_mfma_f32_16x16x32_bf16(af[i], bfr[j], acc[i][j], 0, 0, 0);
    __syncthreads();   // protect LDS before next stage
  }

  // epilogue: C/D layout col = lane&15, row = quad*4 + reg   [verified m89/m91]
  const int r0 = quad * 4;
#pragma unroll
  for (int j = 0; j < 4; ++j) {
    const int col = bn + wn + j * 16 + l15;
    const float bj = bias[col];
#pragma unroll
    for (int i = 0; i < 4; ++i) {
      const int row = bm + wm + i * 16 + r0;
#pragma unroll
      for (int r = 0; r < 4; ++r)
        C[(size_t)(row + r) * Ndim + col] = acc[i][j][r] + bj;
    }
  }
}

// ---------------------------------------------------------------- prefix scan (per batch, per channel)
// pass 1: per-chunk sums. t -> (b, c, d); coalesced on d.
__global__ void chunk_sum(const float* __restrict__ v, float* __restrict__ cs) {
  int t = blockIdx.x * blockDim.x + threadIdx.x;   // NBATCH*NCHUNK*DMODEL
  int d = t % DMODEL;
  int c = (t / DMODEL) % NCHUNK;
  int b = t / (DMODEL * NCHUNK);
  const float* p = v + ((size_t)b * S_LEN + (size_t)c * CHUNK) * DMODEL + d;
  float s = 0.f;
#pragma unroll 8
  for (int r = 0; r < CHUNK; ++r) s += p[(size_t)r * DMODEL];
  cs[t] = s;
}

// pass 2: in-place inclusive prefix within chunk + exclusive sum of prior chunks.
__global__ void scan_apply(float* __restrict__ v, const float* __restrict__ cs) {
  int t = blockIdx.x * blockDim.x + threadIdx.x;
  int d = t % DMODEL;
  int c = (t / DMODEL) % NCHUNK;
  int b = t / (DMODEL * NCHUNK);
  float base = 0.f;
  for (int cc = 0; cc < c; ++cc)             // block-uniform trip count (D % 256 == 0)
    base += cs[((size_t)b * NCHUNK + cc) * DMODEL + d];
  float* p = v + ((size_t)b * S_LEN + (size_t)c * CHUNK) * DMODEL + d;
  float run = base;
#pragma unroll 8
  for (int r = 0; r < CHUNK; ++r) {
    run += p[(size_t)r * DMODEL];
    p[(size_t)r * DMODEL] = run;
  }
}

// ---------------------------------------------------------------- windowed average -> bf16 A2
// out[b,i,d] = (P[i] - P[i-len]) / len,  len = min(i+1, w_h),  h = d>>7
__global__ void winavg_bf16(const float* __restrict__ P, u16* __restrict__ A2) {
  int t = blockIdx.x * blockDim.x + threadIdx.x;   // MROWS*DMODEL
  int d = t % DMODEL;
  int m = t / DMODEL;               // b*S + i
  int i = m & (S_LEN - 1);
  int b = m >> 11;
  int h = d >> 7;
  int w = (2 << h) - 1;             // 2^(h+1)-1
  int len = min(i + 1, w);
  float s = P[(size_t)m * DMODEL + d];
  int jl = i - len;                 // == -1 when window covers prefix start
  if (jl >= 0) s -= P[((size_t)b * S_LEN + jl) * DMODEL + d];
  A2[t] = f2bf(s * (1.0f / (float)len));
}

// ---------------------------------------------------------------- analytic attn_weights [B,H,S,S]
__global__ void attn_weights_kernel(float4* __restrict__ out4) {
  int t = blockIdx.x * blockDim.x + threadIdx.x;   // B*H*S*S/4 = 25165824
  int j0 = (t & 511) << 2;
  int i  = (t >> 9) & (S_LEN - 1);
  int bh = t >> 20;                 // S*S/4 = 2^20
  int h  = bh >= NHEADS ? bh - NHEADS : bh;
  int w  = (2 << h) - 1;
  int len = min(i + 1, w);
  float inv = 1.0f / (float)len;
  int lo = i - w + 1;
  float4 r;
  r.x = (j0     <= i && j0     >= lo) ? inv : 0.f;
  r.y = (j0 + 1 <= i && j0 + 1 >= lo) ? inv : 0.f;
  r.z = (j0 + 2 <= i && j0 + 2 >= lo) ? inv : 0.f;
  r.w = (j0 + 3 <= i && j0 + 3 >= lo) ? inv : 0.f;
  out4[t] = r;
}

// ---------------------------------------------------------------- launch
extern "C" void kernel_launch(void* const* d_in, const int* in_sizes, int n_in,
                              void* d_out, int out_size, void* d_ws, size_t ws_size,
                              hipStream_t stream) {
  const float* hidden = (const float*)d_in[0];
  const float* W_fc   = (const float*)d_in[1];
  const float* b_fc   = (const float*)d_in[2];
  const float* W_proj = (const float*)d_in[3];
  const float* b_proj = (const float*)d_in[4];
  float* outp = (float*)d_out;

  // workspace layout (bytes):
  //   0        : A16   (12,582,912)  hidden bf16, later reused as winavg-output bf16
  //   12582912 : Wfc16 ( 4,718,592)
  //   17301504 : Wpj16 ( 4,718,592)
  //   22020096 : vbuf  (25,165,824)  fp32 v, scanned in place to prefix P
  //   47185920 : csums (   196,608)
  char* ws = (char*)d_ws;
  u16*   A16   = (u16*)(ws);
  u16*   Wfc16 = (u16*)(ws + 12582912);
  u16*   Wpj16 = (u16*)(ws + 17301504);
  float* vbuf  = (float*)(ws + 22020096);
  float* csums = (float*)(ws + 47185920);

  cvt_f32_to_bf16<<<6144, 256, 0, stream>>>((const float4*)hidden, (ushort4*)A16, 1572864);
  cvt_f32_to_bf16<<<2304, 256, 0, stream>>>((const float4*)W_fc,   (ushort4*)Wfc16, 589824);
  cvt_f32_to_bf16<<<2304, 256, 0, stream>>>((const float4*)W_proj, (ushort4*)Wpj16, 589824);

  // GEMM1: v = hidden @ W_fc^T + b_fc
  gemm_bt_bias<<<dim3(DMODEL / 128, MROWS / 128), 256, 0, stream>>>(
      A16, Wfc16, b_fc, vbuf, MROWS, DMODEL, DMODEL);

  // prefix sums along sequence (in place)
  chunk_sum <<<(NBATCH * NCHUNK * DMODEL) / 256, 256, 0, stream>>>(vbuf, csums);
  scan_apply<<<(NBATCH * NCHUNK * DMODEL) / 256, 256, 0, stream>>>(vbuf, csums);

  // windowed average -> bf16 (reuse A16 buffer)
  winavg_bf16<<<(MROWS * DMODEL) / 256, 256, 0, stream>>>(vbuf, A16);

  // GEMM2: out = winavg @ W_proj^T + b_proj  -> d_out[0 : B*S*D]
  gemm_bt_bias<<<dim3(DMODEL / 128, MROWS / 128), 256, 0, stream>>>(
      A16, Wpj16, b_proj, outp, MROWS, DMODEL, DMODEL);

  // attn_weights -> d_out[B*S*D : B*S*D + B*H*S*S]
  attn_weights_kernel<<<(NBATCH * NHEADS * S_LEN * S_LEN / 4) / 256, 256, 0, stream>>>(
      (float4*)(outp + (size_t)MROWS * DMODEL));
}